// Round 3
// baseline (314.730 us; speedup 1.0000x reference)
//
#include <hip/hip_runtime.h>
#include <hip/hip_fp16.h>
#include <stdint.h>

// Luong attention: out = softmax(Q K^T) K,  B=16, Tq=Tk=D=1024, fp32 in/out.
//
// R4 structure: MFMA operands pre-swizzled to fragment-major layout
//   addr_halfs(r, c) = (c>>5)*32768 + r*32 + (c&31)     (per 1024x1024 batch)
// so a 16x16x32 MFMA fragment read (lane = n16*32 + quad*8) is a contiguous
// 1KB wave-coalesced global_load_dwordx4. K-loops have NO LDS and NO barriers.
//
// R6: Q-side conversion ELIMINATED. scores_kernel reads fp32 dec directly
// (lane (n16,quad) -> dec[row][dc*32+quad*8..+8] = 16x128B coalesced runs per
// fragment) and converts in-register (v_cvt_pk_f16_f32 on the VALU pipe,
// concurrent with MFMA). cvt_kernel now only handles enc -> encsw + encTsw
// (the transpose genuinely needs LDS; shared by all 16 q-blocks per batch).
// Saves 96 MiB of cvt traffic (64 read + 32 write) + removes q16 entirely.
// R5 lesson: cvt loads were already compiler-vectorized; it runs at 2.5 TB/s
// for structural reasons, so the win is deleting work, not re-vectorizing.
// R7: resubmit of R6 — the R6 run died to a container-acquisition flake
// (no compile error / no test verdict); kernel re-audited, unchanged.
//
// [cvt]    enc f32 -> encsw (swizzled) + encTsw (LDS 64x64 transpose, swizzled)
// [scores] S = Q K^T (A-frags from fp32 dec, B-frags from encsw), softmax,
//          P -> p16 (swizzled)
// [ctx]    out = P @ enc  (frag loads from p16/encTsw)
// Workspace: p16 32MiB | encsw 32MiB | encTsw 32MiB = 96MiB.

typedef _Float16 half_t;
typedef __attribute__((ext_vector_type(8))) _Float16 f16x8;
typedef __attribute__((ext_vector_type(4))) float f32x4;

// ---------------------------------------------------------------------------
// Kernel 1: enc fp32 -> fp16 swizzled (direct + transposed).
// grid (rt=16, ct=16, b=16), block 256.
// ---------------------------------------------------------------------------
__global__ __launch_bounds__(256) void cvt_kernel(
    const float* __restrict__ enc,
    half_t* __restrict__ encsw, half_t* __restrict__ encTsw) {
    __shared__ half_t lt[64 * 65];  // pad 65: conflict-free transpose
    const int b = blockIdx.z;
    const int rt = blockIdx.x, ct = blockIdx.y;
    const int t = threadIdx.x;
    const int r = t >> 2;           // local row 0..63
    const int c0 = (t & 3) << 4;    // local col segment {0,16,32,48}
    const size_t bofs = (size_t)b << 20;

    const float* src = enc + bofs + (size_t)(rt * 64 + r) * 1024 + ct * 64 + c0;
    const float4* s4 = (const float4*)src;
    const float4 f0 = s4[0];
    const float4 f1 = s4[1];
    const float4 f2 = s4[2];
    const float4 f3 = s4[3];

    union { half_t h[16]; uint4 q[2]; } v;
    v.h[0]  = (half_t)f0.x; v.h[1]  = (half_t)f0.y;
    v.h[2]  = (half_t)f0.z; v.h[3]  = (half_t)f0.w;
    v.h[4]  = (half_t)f1.x; v.h[5]  = (half_t)f1.y;
    v.h[6]  = (half_t)f1.z; v.h[7]  = (half_t)f1.w;
    v.h[8]  = (half_t)f2.x; v.h[9]  = (half_t)f2.y;
    v.h[10] = (half_t)f2.z; v.h[11] = (half_t)f2.w;
    v.h[12] = (half_t)f3.x; v.h[13] = (half_t)f3.y;
    v.h[14] = (half_t)f3.z; v.h[15] = (half_t)f3.w;

    // direct swizzled write: element (gr, gc+i) -> (gc>>5)*32768 + gr*32 + (gc&31) + i
    {
        const int gr = rt * 64 + r, gc = ct * 64 + c0;
        half_t* dst = encsw + bofs
                      + (size_t)(gc >> 5) * 32768 + gr * 32 + (gc & 31);
        ((uint4*)dst)[0] = v.q[0];
        ((uint4*)dst)[1] = v.q[1];
    }

#pragma unroll
    for (int i = 0; i < 16; ++i) lt[r * 65 + c0 + i] = v.h[i];
    __syncthreads();
    // thread now holds (key = rt*64 + c0 + i, d = ct*64 + r), keys contiguous
    union { half_t h[16]; uint4 q[2]; } w;
#pragma unroll
    for (int i = 0; i < 16; ++i) w.h[i] = lt[(c0 + i) * 65 + r];
    const int gk = rt * 64 + c0, gd = ct * 64 + r;
    half_t* dstT = encTsw + bofs
                   + (size_t)(gk >> 5) * 32768 + gd * 32 + (gk & 31);
    ((uint4*)dstT)[0] = w.q[0];
    ((uint4*)dstT)[1] = w.q[1];
}

// ---------------------------------------------------------------------------
// Kernel 2: S-resident scores + softmax. grid 256 x 512 thr (8 waves).
// Block = (batch, 64 q-rows); wave w owns keys {h*512 + w*64 ..+64}, h=0,1.
// A-frags read from fp32 dec directly (R6) + cvt in-register; B-frags from
// encsw. acc[4][8] 16x16 frags = 128 VGPR, statically indexed. No LDS/barrier
// in the K-loop.
// ---------------------------------------------------------------------------
__global__ __launch_bounds__(512, 2) void scores_kernel(
    const float* __restrict__ dec, const half_t* __restrict__ encsw,
    half_t* __restrict__ p16) {
    __shared__ float red[512];
    __shared__ float redg[64];

    const int l = blockIdx.x;
    const int xcd = l & 7, idx = l >> 3;
    const int b = xcd + ((idx >> 4) << 3);   // 2 batches per XCD: encsw L2-resident
    const int qbase = (idx & 15) * 64;

    const int tid = threadIdx.x;
    const int w = tid >> 6, lane = tid & 63, quad = lane >> 4, n16 = lane & 15;
    const int laneoff = n16 * 32 + quad * 8;   // frag lane offset within 1KB chunk
    const size_t bofs = (size_t)b << 20;

    // dc-invariant fp32 A-operand row pointers (row = qbase + rb*16 + n16)
    const float* qrow[4];
#pragma unroll
    for (int rb = 0; rb < 4; ++rb)
        qrow[rb] = dec + bofs + (size_t)(qbase + rb * 16 + n16) * 1024 + quad * 8;

    f32x4 acc[4][8];
#pragma unroll
    for (int rb = 0; rb < 4; ++rb)
#pragma unroll
        for (int cf = 0; cf < 8; ++cf) acc[rb][cf] = (f32x4){0.f, 0.f, 0.f, 0.f};

    for (int dc = 0; dc < 32; ++dc) {
        const half_t* ec = encsw + bofs + (size_t)dc * 32768;
        // issue all loads first: 8x dwordx4 fp32 (A) + 8x dwordx4 fp16 (B)
        float4 q0[4], q1[4];
#pragma unroll
        for (int rb = 0; rb < 4; ++rb) {
            const float4* qp = (const float4*)(qrow[rb] + dc * 32);
            q0[rb] = qp[0];
            q1[rb] = qp[1];
        }
        f16x8 bf[8];
#pragma unroll
        for (int h = 0; h < 2; ++h)
#pragma unroll
            for (int cb = 0; cb < 4; ++cb)
                bf[h * 4 + cb] = *(const f16x8*)(
                    ec + (h * 512 + w * 64 + cb * 16) * 32 + laneoff);
        // convert A to fp16 fragments (VALU pipe, overlaps MFMA pipe)
        f16x8 af[4];
#pragma unroll
        for (int rb = 0; rb < 4; ++rb) {
            union { half_t h[8]; f16x8 v; } u;
            u.h[0] = (half_t)q0[rb].x; u.h[1] = (half_t)q0[rb].y;
            u.h[2] = (half_t)q0[rb].z; u.h[3] = (half_t)q0[rb].w;
            u.h[4] = (half_t)q1[rb].x; u.h[5] = (half_t)q1[rb].y;
            u.h[6] = (half_t)q1[rb].z; u.h[7] = (half_t)q1[rb].w;
            af[rb] = u.v;
        }
#pragma unroll
        for (int rb = 0; rb < 4; ++rb)
#pragma unroll
            for (int cf = 0; cf < 8; ++cf)
                acc[rb][cf] = __builtin_amdgcn_mfma_f32_16x16x32_f16(
                    af[rb], bf[cf], acc[rb][cf], 0, 0, 0);
    }

    // ---- softmax over the 1024 cols held across the 8 waves ----
    float mrow[4][4], srow[4][4];
#pragma unroll
    for (int rb = 0; rb < 4; ++rb)
#pragma unroll
        for (int r = 0; r < 4; ++r) {
            float m = -1e30f;
#pragma unroll
            for (int cf = 0; cf < 8; ++cf) m = fmaxf(m, acc[rb][cf][r]);
#pragma unroll
            for (int off = 1; off < 16; off <<= 1)
                m = fmaxf(m, __shfl_xor(m, off, 64));
            mrow[rb][r] = m;
        }
    if (n16 == 0) {
#pragma unroll
        for (int rb = 0; rb < 4; ++rb)
#pragma unroll
            for (int r = 0; r < 4; ++r)
                red[w * 64 + rb * 16 + quad * 4 + r] = mrow[rb][r];
    }
    __syncthreads();
    if (tid < 64) {
        float g = red[tid];
#pragma unroll
        for (int ww = 1; ww < 8; ++ww) g = fmaxf(g, red[ww * 64 + tid]);
        redg[tid] = g;
    }
    __syncthreads();
#pragma unroll
    for (int rb = 0; rb < 4; ++rb)
#pragma unroll
        for (int r = 0; r < 4; ++r) mrow[rb][r] = redg[rb * 16 + quad * 4 + r];
    __syncthreads();  // maxes consumed; red reused for sums

#pragma unroll
    for (int rb = 0; rb < 4; ++rb)
#pragma unroll
        for (int r = 0; r < 4; ++r) {
            float s = 0.f;
#pragma unroll
            for (int cf = 0; cf < 8; ++cf) {
                float p = __expf(acc[rb][cf][r] - mrow[rb][r]);
                acc[rb][cf][r] = p;
                s += p;
            }
#pragma unroll
            for (int off = 1; off < 16; off <<= 1) s += __shfl_xor(s, off, 64);
            srow[rb][r] = s;
        }
    if (n16 == 0) {
#pragma unroll
        for (int rb = 0; rb < 4; ++rb)
#pragma unroll
            for (int r = 0; r < 4; ++r)
                red[w * 64 + rb * 16 + quad * 4 + r] = srow[rb][r];
    }
    __syncthreads();
    if (tid < 64) {
        float g = 0.f;
#pragma unroll
        for (int ww = 0; ww < 8; ++ww) g += red[ww * 64 + tid];
        redg[tid] = g;
    }
    __syncthreads();
#pragma unroll
    for (int rb = 0; rb < 4; ++rb)
#pragma unroll
        for (int r = 0; r < 4; ++r)
            srow[rb][r] = 1.0f / redg[rb * 16 + quad * 4 + r];

    // ---- store normalized P as fp16 in swizzled layout (ctx A-operand) ----
#pragma unroll
    for (int rb = 0; rb < 4; ++rb)
#pragma unroll
        for (int cf = 0; cf < 8; ++cf) {
            const int colbase = ((cf >> 2) << 9) + w * 64 + ((cf & 3) << 4);
            half_t* pp = p16 + bofs + (size_t)(colbase >> 5) * 32768
                         + (colbase & 31) + n16;
#pragma unroll
            for (int r = 0; r < 4; ++r) {
                const int row = qbase + rb * 16 + quad * 4 + r;
                pp[row * 32] = (half_t)(acc[rb][cf][r] * srow[rb][r]);
            }
        }
}

// ---------------------------------------------------------------------------
// Kernel 3: out = P16 @ enc (NT via encTsw). grid 512 x 256 thr (4 waves).
// Block tile 128q x 256d; wave (wr,wc) does 64q x 128d: acc[4][8] = 128 VGPR.
// K-loop: 12 coalesced frag loads + 32 MFMA per kc, no LDS, no barriers.
// ---------------------------------------------------------------------------
__global__ __launch_bounds__(256, 2) void ctx_kernel(
    const half_t* __restrict__ p16, const half_t* __restrict__ encTsw,
    float* __restrict__ out) {
    const int l = blockIdx.x;
    const int xcd = l & 7, idx = l >> 3;        // idx 0..63
    const int b = xcd + ((idx >> 5) << 3);
    const int rem = idx & 31;
    const int qt = rem >> 2, dt = rem & 3;
    const int tid = threadIdx.x;
    const int w = tid >> 6, lane = tid & 63, quad = lane >> 4, n16 = lane & 15;
    const int wr = w >> 1, wc = w & 1;
    const int laneoff = n16 * 32 + quad * 8;
    const size_t bofs = (size_t)b << 20;

    const int arow0 = qt * 128 + wr * 64;    // + rb*16
    const int brow0 = dt * 256 + wc * 128;   // + cb*16

    f32x4 acc[4][8];
#pragma unroll
    for (int i = 0; i < 4; ++i)
#pragma unroll
        for (int j = 0; j < 8; ++j) acc[i][j] = (f32x4){0.f, 0.f, 0.f, 0.f};

    for (int kc = 0; kc < 32; ++kc) {
        const half_t* ac = p16 + bofs + (size_t)kc * 32768;
        const half_t* bc = encTsw + bofs + (size_t)kc * 32768;
        f16x8 af[4], bf[8];
#pragma unroll
        for (int rb = 0; rb < 4; ++rb)
            af[rb] = *(const f16x8*)(ac + (arow0 + rb * 16) * 32 + laneoff);
#pragma unroll
        for (int cb = 0; cb < 8; ++cb)
            bf[cb] = *(const f16x8*)(bc + (brow0 + cb * 16) * 32 + laneoff);
#pragma unroll
        for (int rb = 0; rb < 4; ++rb)
#pragma unroll
            for (int cb = 0; cb < 8; ++cb)
                acc[rb][cb] = __builtin_amdgcn_mfma_f32_16x16x32_f16(
                    af[rb], bf[cb], acc[rb][cb], 0, 0, 0);
    }

#pragma unroll
    for (int rb = 0; rb < 4; ++rb)
#pragma unroll
        for (int cb = 0; cb < 8; ++cb)
#pragma unroll
            for (int r = 0; r < 4; ++r) {
                const int row = arow0 + rb * 16 + quad * 4 + r;
                const int col = brow0 + cb * 16 + n16;
                out[bofs + (size_t)row * 1024 + col] = acc[rb][cb][r];
            }
}

extern "C" void kernel_launch(void* const* d_in, const int* in_sizes, int n_in,
                              void* d_out, int out_size, void* d_ws, size_t ws_size,
                              hipStream_t stream) {
    (void)in_sizes; (void)n_in; (void)out_size; (void)ws_size;
    const float* dec = (const float*)d_in[0];   // decoder_hidden  [16,1024,1024] f32
    const float* enc = (const float*)d_in[1];   // encoder_outputs [16,1024,1024] f32
    float* out = (float*)d_out;

    // workspace: p16 | encsw | encTsw, 32MiB each (96MiB total)
    half_t* p16    = (half_t*)d_ws;
    half_t* encsw  = p16 + ((size_t)16 << 20);
    half_t* encTsw = encsw + ((size_t)16 << 20);

    cvt_kernel<<<dim3(16, 16, 16), 256, 0, stream>>>(enc, encsw, encTsw);
    scores_kernel<<<dim3(256), 512, 0, stream>>>(dec, encsw, p16);
    ctx_kernel<<<dim3(512), 256, 0, stream>>>(p16, encTsw, out);
}

// Round 6
// 266.454 us; speedup vs baseline: 1.1812x; 1.1812x over previous
//
#include <hip/hip_runtime.h>
#include <hip/hip_fp16.h>
#include <stdint.h>

// Luong attention: out = softmax(Q K^T) K,  B=16, Tq=Tk=D=1024, fp32 in/out.
//
// R4 structure: MFMA operands pre-swizzled to fragment-major layout
//   addr_halfs(r, c) = (c>>5)*32768 + r*32 + (c&31)     (per 1024x1024 batch)
// so a 16x16x32 MFMA fragment read (lane = n16*32 + quad*8) is a contiguous
// 1KB wave-coalesced global_load_dwordx4.
//
// R6: cvt halved (enc-only). R7 profile: scores regressed 65->128us because
// in-K-loop fp32 A-loads + cvt chain broke the MFMA pipeline (MfmaUtil 10.6%).
// R9/R10: Q staged per block into LDS as fp16 in TWO 512-col phases
// (qlds[16][64][32] fp16 = 64 KiB; stage ph0 / K-loop dc 0..15 / barrier /
// stage ph1 / K-loop dc 16..31). Slot-XOR (s ^= (row>>1)&3) keeps both LDS
// write and ds_read_b128 frag read bank-even. K-loop: 8 global B-frag loads
// + 4 ds_reads + 32 MFMA, no in-loop cvt, no in-loop barriers. red/redg
// alias qlds after the K-loop (barrier-guarded) -> LDS exactly 65536 B.
// R10 = R9 resubmitted verbatim: R9 died to "container failed twice" with no
// test verdict; full audit found no OOB/divergent-barrier/launch-config
// issue, and the R6->R7 precedent (identical resubmit passed) plus the
// round-3 infra pathology (406s npz push) point to infra flake.
//
// [cvt]    enc f32 -> encsw (swizzled) + encTsw (LDS 64x64 transpose, swizzled)
// [scores] stage Q->LDS fp16 (2 phases); S = Q K^T (A from LDS, B from encsw),
//          softmax, P -> p16 (swizzled)
// [ctx]    out = P @ enc  (frag loads from p16/encTsw)
// Workspace: p16 32MiB | encsw 32MiB | encTsw 32MiB = 96MiB.

typedef _Float16 half_t;
typedef __attribute__((ext_vector_type(8))) _Float16 f16x8;
typedef __attribute__((ext_vector_type(4))) float f32x4;

// ---------------------------------------------------------------------------
// Kernel 1: enc fp32 -> fp16 swizzled (direct + transposed).
// grid (rt=16, ct=16, b=16), block 256.
// ---------------------------------------------------------------------------
__global__ __launch_bounds__(256) void cvt_kernel(
    const float* __restrict__ enc,
    half_t* __restrict__ encsw, half_t* __restrict__ encTsw) {
    __shared__ half_t lt[64 * 65];  // pad 65: conflict-free transpose
    const int b = blockIdx.z;
    const int rt = blockIdx.x, ct = blockIdx.y;
    const int t = threadIdx.x;
    const int r = t >> 2;           // local row 0..63
    const int c0 = (t & 3) << 4;    // local col segment {0,16,32,48}
    const size_t bofs = (size_t)b << 20;

    const float* src = enc + bofs + (size_t)(rt * 64 + r) * 1024 + ct * 64 + c0;
    const float4* s4 = (const float4*)src;
    const float4 f0 = s4[0];
    const float4 f1 = s4[1];
    const float4 f2 = s4[2];
    const float4 f3 = s4[3];

    union { half_t h[16]; uint4 q[2]; } v;
    v.h[0]  = (half_t)f0.x; v.h[1]  = (half_t)f0.y;
    v.h[2]  = (half_t)f0.z; v.h[3]  = (half_t)f0.w;
    v.h[4]  = (half_t)f1.x; v.h[5]  = (half_t)f1.y;
    v.h[6]  = (half_t)f1.z; v.h[7]  = (half_t)f1.w;
    v.h[8]  = (half_t)f2.x; v.h[9]  = (half_t)f2.y;
    v.h[10] = (half_t)f2.z; v.h[11] = (half_t)f2.w;
    v.h[12] = (half_t)f3.x; v.h[13] = (half_t)f3.y;
    v.h[14] = (half_t)f3.z; v.h[15] = (half_t)f3.w;

    // direct swizzled write: element (gr, gc+i) -> (gc>>5)*32768 + gr*32 + (gc&31) + i
    {
        const int gr = rt * 64 + r, gc = ct * 64 + c0;
        half_t* dst = encsw + bofs
                      + (size_t)(gc >> 5) * 32768 + gr * 32 + (gc & 31);
        ((uint4*)dst)[0] = v.q[0];
        ((uint4*)dst)[1] = v.q[1];
    }

#pragma unroll
    for (int i = 0; i < 16; ++i) lt[r * 65 + c0 + i] = v.h[i];
    __syncthreads();
    // thread now holds (key = rt*64 + c0 + i, d = ct*64 + r), keys contiguous
    union { half_t h[16]; uint4 q[2]; } w;
#pragma unroll
    for (int i = 0; i < 16; ++i) w.h[i] = lt[(c0 + i) * 65 + r];
    const int gk = rt * 64 + c0, gd = ct * 64 + r;
    half_t* dstT = encTsw + bofs
                   + (size_t)(gk >> 5) * 32768 + gd * 32 + (gk & 31);
    ((uint4*)dstT)[0] = w.q[0];
    ((uint4*)dstT)[1] = w.q[1];
}

// ---------------------------------------------------------------------------
// Kernel 2: S-resident scores + softmax. grid 256 x 512 thr (8 waves).
// Block = (batch, 64 q-rows); wave w owns keys {h*512 + w*64 ..+64}, h=0,1.
// Q staged in LDS fp16, 2 phases of 16 chunks (64 KiB). acc[4][8] 16x16
// frags, statically indexed. K-loop: 4 ds_read + 8 global frag loads +
// 32 MFMA, no in-loop barriers.
// ---------------------------------------------------------------------------
__global__ __launch_bounds__(512, 2) void scores_kernel(
    const float* __restrict__ dec, const half_t* __restrict__ encsw,
    half_t* __restrict__ p16) {
    // 64 KiB: qlds for the K-loop; red/redg alias it afterwards (guarded by
    // a barrier after the K-loop).
    __shared__ __align__(16) unsigned char smem[65536];
    half_t* qlds = (half_t*)smem;           // [16 chunks][64 rows][32 cols]
    float* red = (float*)smem;              // [512]
    float* redg = (float*)(smem + 2048);    // [64]

    const int l = blockIdx.x;
    const int xcd = l & 7, idx = l >> 3;
    const int b = xcd + ((idx >> 4) << 3);   // 2 batches per XCD: encsw L2-resident
    const int qbase = (idx & 15) * 64;

    const int tid = threadIdx.x;
    const int w = tid >> 6, lane = tid & 63, quad = lane >> 4, n16 = lane & 15;
    const int laneoff = n16 * 32 + quad * 8;   // frag lane offset within 1KB chunk
    const size_t bofs = (size_t)b << 20;

    // staging decomposition (same for both phases)
    const int sr = tid >> 3;       // 0..63 local row
    const int sp = tid & 7;        // 0..7
    const int sg = (sr >> 1) & 3;  // slot-XOR key
    const float* srcrow = dec + bofs + (size_t)(qbase + sr) * 1024;

    // dc-invariant A-frag LDS offsets (halfs): row lr = rb*16+n16, slot quad^g
    int aoff[4];
#pragma unroll
    for (int rb = 0; rb < 4; ++rb) {
        const int lr = rb * 16 + n16;
        aoff[rb] = lr * 32 + ((quad ^ ((lr >> 1) & 3)) << 3);
    }

    f32x4 acc[4][8];
#pragma unroll
    for (int rb = 0; rb < 4; ++rb)
#pragma unroll
        for (int cf = 0; cf < 8; ++cf) acc[rb][cf] = (f32x4){0.f, 0.f, 0.f, 0.f};

#pragma unroll
    for (int ph = 0; ph < 2; ++ph) {
        if (ph) __syncthreads();   // all phase-0 qlds reads done before rewrite
        // ---- stage 512 cols of Q (cols ph*512 ..+512) into LDS as fp16 ----
#pragma unroll
        for (int k = 0; k < 4; ++k) {
            const int c0 = sp * 16 + k * 128;          // local col 0..511
            const float4* spv = (const float4*)(srcrow + ph * 512 + c0);
            const float4 a0 = spv[0], a1 = spv[1], a2 = spv[2], a3 = spv[3];
            union { half_t h[16]; uint4 q[2]; } u;
            u.h[0]  = (half_t)a0.x; u.h[1]  = (half_t)a0.y;
            u.h[2]  = (half_t)a0.z; u.h[3]  = (half_t)a0.w;
            u.h[4]  = (half_t)a1.x; u.h[5]  = (half_t)a1.y;
            u.h[6]  = (half_t)a1.z; u.h[7]  = (half_t)a1.w;
            u.h[8]  = (half_t)a2.x; u.h[9]  = (half_t)a2.y;
            u.h[10] = (half_t)a2.z; u.h[11] = (half_t)a2.w;
            u.h[12] = (half_t)a3.x; u.h[13] = (half_t)a3.y;
            u.h[14] = (half_t)a3.z; u.h[15] = (half_t)a3.w;
            const int chunk = c0 >> 5;                 // local chunk 0..15
            const int s0 = (c0 & 31) >> 3;             // {0,2}
            half_t* base = qlds + chunk * 2048 + sr * 32;
            ((uint4*)(base + ((s0 ^ sg) << 3)))[0] = u.q[0];
            ((uint4*)(base + (((s0 + 1) ^ sg) << 3)))[0] = u.q[1];
        }
        __syncthreads();

        for (int dcl = 0; dcl < 16; ++dcl) {
            const int dc = ph * 16 + dcl;
            const half_t* ec = encsw + bofs + (size_t)dc * 32768;
            f16x8 bf[8];
#pragma unroll
            for (int h = 0; h < 2; ++h)
#pragma unroll
                for (int cb = 0; cb < 4; ++cb)
                    bf[h * 4 + cb] = *(const f16x8*)(
                        ec + (h * 512 + w * 64 + cb * 16) * 32 + laneoff);
            f16x8 af[4];
#pragma unroll
            for (int rb = 0; rb < 4; ++rb)
                af[rb] = *(const f16x8*)(qlds + dcl * 2048 + aoff[rb]);
#pragma unroll
            for (int rb = 0; rb < 4; ++rb)
#pragma unroll
                for (int cf = 0; cf < 8; ++cf)
                    acc[rb][cf] = __builtin_amdgcn_mfma_f32_16x16x32_f16(
                        af[rb], bf[cf], acc[rb][cf], 0, 0, 0);
        }
    }
    __syncthreads();  // qlds dead; red/redg alias it from here on

    // ---- softmax over the 1024 cols held across the 8 waves ----
    float mrow[4][4], srow[4][4];
#pragma unroll
    for (int rb = 0; rb < 4; ++rb)
#pragma unroll
        for (int r = 0; r < 4; ++r) {
            float m = -1e30f;
#pragma unroll
            for (int cf = 0; cf < 8; ++cf) m = fmaxf(m, acc[rb][cf][r]);
#pragma unroll
            for (int off = 1; off < 16; off <<= 1)
                m = fmaxf(m, __shfl_xor(m, off, 64));
            mrow[rb][r] = m;
        }
    if (n16 == 0) {
#pragma unroll
        for (int rb = 0; rb < 4; ++rb)
#pragma unroll
            for (int r = 0; r < 4; ++r)
                red[w * 64 + rb * 16 + quad * 4 + r] = mrow[rb][r];
    }
    __syncthreads();
    if (tid < 64) {
        float g = red[tid];
#pragma unroll
        for (int ww = 1; ww < 8; ++ww) g = fmaxf(g, red[ww * 64 + tid]);
        redg[tid] = g;
    }
    __syncthreads();
#pragma unroll
    for (int rb = 0; rb < 4; ++rb)
#pragma unroll
        for (int r = 0; r < 4; ++r) mrow[rb][r] = redg[rb * 16 + quad * 4 + r];
    __syncthreads();  // maxes consumed; red reused for sums

#pragma unroll
    for (int rb = 0; rb < 4; ++rb)
#pragma unroll
        for (int r = 0; r < 4; ++r) {
            float s = 0.f;
#pragma unroll
            for (int cf = 0; cf < 8; ++cf) {
                float p = __expf(acc[rb][cf][r] - mrow[rb][r]);
                acc[rb][cf][r] = p;
                s += p;
            }
#pragma unroll
            for (int off = 1; off < 16; off <<= 1) s += __shfl_xor(s, off, 64);
            srow[rb][r] = s;
        }
    if (n16 == 0) {
#pragma unroll
        for (int rb = 0; rb < 4; ++rb)
#pragma unroll
            for (int r = 0; r < 4; ++r)
                red[w * 64 + rb * 16 + quad * 4 + r] = srow[rb][r];
    }
    __syncthreads();
    if (tid < 64) {
        float g = 0.f;
#pragma unroll
        for (int ww = 0; ww < 8; ++ww) g += red[ww * 64 + tid];
        redg[tid] = g;
    }
    __syncthreads();
#pragma unroll
    for (int rb = 0; rb < 4; ++rb)
#pragma unroll
        for (int r = 0; r < 4; ++r)
            srow[rb][r] = 1.0f / redg[rb * 16 + quad * 4 + r];

    // ---- store normalized P as fp16 in swizzled layout (ctx A-operand) ----
#pragma unroll
    for (int rb = 0; rb < 4; ++rb)
#pragma unroll
        for (int cf = 0; cf < 8; ++cf) {
            const int colbase = ((cf >> 2) << 9) + w * 64 + ((cf & 3) << 4);
            half_t* pp = p16 + bofs + (size_t)(colbase >> 5) * 32768
                         + (colbase & 31) + n16;
#pragma unroll
            for (int r = 0; r < 4; ++r) {
                const int row = qbase + rb * 16 + quad * 4 + r;
                pp[row * 32] = (half_t)(acc[rb][cf][r] * srow[rb][r]);
            }
        }
}

// ---------------------------------------------------------------------------
// Kernel 3: out = P16 @ enc (NT via encTsw). grid 512 x 256 thr (4 waves).
// Block tile 128q x 256d; wave (wr,wc) does 64q x 128d: acc[4][8] = 128 VGPR.
// K-loop: 12 coalesced frag loads + 32 MFMA per kc, no LDS, no barriers.
// ---------------------------------------------------------------------------
__global__ __launch_bounds__(256, 2) void ctx_kernel(
    const half_t* __restrict__ p16, const half_t* __restrict__ encTsw,
    float* __restrict__ out) {
    const int l = blockIdx.x;
    const int xcd = l & 7, idx = l >> 3;        // idx 0..63
    const int b = xcd + ((idx >> 5) << 3);
    const int rem = idx & 31;
    const int qt = rem >> 2, dt = rem & 3;
    const int tid = threadIdx.x;
    const int w = tid >> 6, lane = tid & 63, quad = lane >> 4, n16 = lane & 15;
    const int wr = w >> 1, wc = w & 1;
    const int laneoff = n16 * 32 + quad * 8;
    const size_t bofs = (size_t)b << 20;

    const int arow0 = qt * 128 + wr * 64;    // + rb*16
    const int brow0 = dt * 256 + wc * 128;   // + cb*16

    f32x4 acc[4][8];
#pragma unroll
    for (int i = 0; i < 4; ++i)
#pragma unroll
        for (int j = 0; j < 8; ++j) acc[i][j] = (f32x4){0.f, 0.f, 0.f, 0.f};

    for (int kc = 0; kc < 32; ++kc) {
        const half_t* ac = p16 + bofs + (size_t)kc * 32768;
        const half_t* bc = encTsw + bofs + (size_t)kc * 32768;
        f16x8 af[4], bf[8];
#pragma unroll
        for (int rb = 0; rb < 4; ++rb)
            af[rb] = *(const f16x8*)(ac + (arow0 + rb * 16) * 32 + laneoff);
#pragma unroll
        for (int cb = 0; cb < 8; ++cb)
            bf[cb] = *(const f16x8*)(bc + (brow0 + cb * 16) * 32 + laneoff);
#pragma unroll
        for (int rb = 0; rb < 4; ++rb)
#pragma unroll
            for (int cb = 0; cb < 8; ++cb)
                acc[rb][cb] = __builtin_amdgcn_mfma_f32_16x16x32_f16(
                    af[rb], bf[cb], acc[rb][cb], 0, 0, 0);
    }

#pragma unroll
    for (int rb = 0; rb < 4; ++rb)
#pragma unroll
        for (int cb = 0; cb < 8; ++cb)
#pragma unroll
            for (int r = 0; r < 4; ++r) {
                const int row = arow0 + rb * 16 + quad * 4 + r;
                const int col = brow0 + cb * 16 + n16;
                out[bofs + (size_t)row * 1024 + col] = acc[rb][cb][r];
            }
}

extern "C" void kernel_launch(void* const* d_in, const int* in_sizes, int n_in,
                              void* d_out, int out_size, void* d_ws, size_t ws_size,
                              hipStream_t stream) {
    (void)in_sizes; (void)n_in; (void)out_size; (void)ws_size;
    const float* dec = (const float*)d_in[0];   // decoder_hidden  [16,1024,1024] f32
    const float* enc = (const float*)d_in[1];   // encoder_outputs [16,1024,1024] f32
    float* out = (float*)d_out;

    // workspace: p16 | encsw | encTsw, 32MiB each (96MiB total)
    half_t* p16    = (half_t*)d_ws;
    half_t* encsw  = p16 + ((size_t)16 << 20);
    half_t* encTsw = encsw + ((size_t)16 << 20);

    cvt_kernel<<<dim3(16, 16, 16), 256, 0, stream>>>(enc, encsw, encTsw);
    scores_kernel<<<dim3(256), 512, 0, stream>>>(dec, encsw, p16);
    ctx_kernel<<<dim3(512), 256, 0, stream>>>(p16, encTsw, out);
}